// Round 1
// baseline (203.433 us; speedup 1.0000x reference)
//
#include <hip/hip_runtime.h>

// JointAngleLoss: loss = sum(coplane) + sum(relu(-vd1)^2 like) + ... over B samples x 5 fingers.
// Pure memory-bound streaming reduction: 132 MB in, 4 B out.

constexpr int BLOCK = 128;           // threads per block == samples per block
constexpr int FPS   = 63;            // floats per sample (21 joints x 3)
constexpr int LDS_FLOATS = BLOCK * FPS;    // 8064 floats = 32256 B
constexpr int NF4  = LDS_FLOATS / 4;       // 2016 float4 per block
constexpr int TAIL = NF4 - 15 * BLOCK;     // 96

__global__ __launch_bounds__(BLOCK, 2) void jal_kernel(
    const float* __restrict__ pose, float* __restrict__ out) {
  __shared__ float lds[LDS_FLOATS];
  __shared__ float wsum[BLOCK / 64];

  const int tid = threadIdx.x;

  // ---- Stage 128 samples (32256 B) into LDS with coalesced float4 loads ----
  // Block base byte offset = blockIdx.x * 32256, multiple of 16 -> aligned.
  const float4* __restrict__ gsrc =
      (const float4*)(pose + (size_t)blockIdx.x * LDS_FLOATS);
  float4* ldst = (float4*)lds;

  float4 tmp[15];
#pragma unroll
  for (int i = 0; i < 15; ++i) tmp[i] = gsrc[tid + i * BLOCK];
  float4 tail;
  if (tid < TAIL) tail = gsrc[tid + 15 * BLOCK];
#pragma unroll
  for (int i = 0; i < 15; ++i) ldst[tid + i * BLOCK] = tmp[i];
  if (tid < TAIL) ldst[tid + 15 * BLOCK] = tail;

  __syncthreads();

  // ---- Each thread computes one sample's loss from LDS ----
  // LDS read addresses: tid*63 + k; stride 63 == -1 mod 32 banks -> 2-way (free).
  const float* s = &lds[tid * FPS];
  float loss = 0.0f;

#pragma unroll
  for (int f = 0; f < 5; ++f) {
    const float* j = s + 12 * f;  // joint (4f) at float offset 12f
    const float j0x = j[0],  j0y = j[1],  j0z = j[2];
    const float j1x = j[3],  j1y = j[4],  j1z = j[5];
    const float j2x = j[6],  j2y = j[7],  j2z = j[8];
    const float j3x = j[9],  j3y = j[10], j3z = j[11];
    const float j4x = j[12], j4y = j[13], j4z = j[14];

    const float b1x = j1x - j0x, b1y = j1y - j0y, b1z = j1z - j0z;
    const float b2x = j2x - j1x, b2y = j2y - j1y, b2z = j2z - j1z;
    const float b3x = j3x - j2x, b3y = j3y - j2y, b3z = j3z - j2z;
    const float b4x = j4x - j3x, b4y = j4y - j3y, b4z = j4z - j3z;

    // rot_tip = cross(b4, b3)
    const float rtx = b4y * b3z - b4z * b3y;
    const float rty = b4z * b3x - b4x * b3z;
    const float rtz = b4x * b3y - b4y * b3x;
    // rot_mid = cross(b3, b2)
    const float rmx = b3y * b2z - b3z * b2y;
    const float rmy = b3z * b2x - b3x * b2z;
    const float rmz = b3x * b2y - b3y * b2x;
    // rot_palm = cross(b2, b1)
    const float rpx = b2y * b1z - b2z * b1y;
    const float rpy = b2z * b1x - b2x * b1z;
    const float rpz = b2x * b1y - b2y * b1x;

    const float coplane =
        (rpx + rmx) * b4x + (rpy + rmy) * b4y + (rpz + rmz) * b4z;
    const float vd1 = rtx * rmx + rty * rmy + rtz * rmz;
    const float vd2 = rpx * rmx + rpy * rmy + rpz * rmz;

    loss += coplane;
    if (vd1 < 0.0f) loss += vd1 * vd1;
    if (vd2 < 0.0f) loss += vd2 * vd2;
  }

  // ---- Reduction: wave shuffle -> block LDS -> one atomic per block ----
#pragma unroll
  for (int o = 32; o > 0; o >>= 1) loss += __shfl_down(loss, o, 64);

  if ((tid & 63) == 0) wsum[tid >> 6] = loss;
  __syncthreads();
  if (tid == 0) {
    float blocksum = 0.0f;
#pragma unroll
    for (int w = 0; w < BLOCK / 64; ++w) blocksum += wsum[w];
    atomicAdd(out, blocksum);
  }
}

extern "C" void kernel_launch(void* const* d_in, const int* in_sizes, int n_in,
                              void* d_out, int out_size, void* d_ws, size_t ws_size,
                              hipStream_t stream) {
  const float* pose = (const float*)d_in[0];
  float* out = (float*)d_out;
  const int B = in_sizes[0] / FPS;  // 524288

  // d_out is poisoned 0xAA before every launch -> zero it (capture-safe).
  hipMemsetAsync(d_out, 0, sizeof(float) * out_size, stream);

  const int grid = B / BLOCK;  // 524288 / 128 = 4096, exact
  jal_kernel<<<grid, BLOCK, 0, stream>>>(pose, out);
}

// Round 5
// 186.894 us; speedup vs baseline: 1.0885x; 1.0885x over previous
//
#include <hip/hip_runtime.h>

// JointAngleLoss: loss over B samples x 5 fingers. Memory-bound streaming
// reduction: 132 MB in, 4 B out.
//
// Structure: kernel 1 stages 128 samples/block into LDS with coalesced
// float4 loads, computes per-sample loss, writes ONE partial per block to
// d_ws (no atomics). Kernel 2 (single block) reduces the 4096 partials and
// writes d_out (so no memset node needed).

constexpr int BLOCK = 128;                 // threads per block == samples per block
constexpr int FPS   = 63;                  // floats per sample (21 joints x 3)
constexpr int LDS_FLOATS = BLOCK * FPS;    // 8064 floats = 32256 B
constexpr int NF4  = LDS_FLOATS / 4;       // 2016 float4 per block
constexpr int TAIL = NF4 - 15 * BLOCK;     // 96

__global__ __launch_bounds__(BLOCK, 2) void jal_partial(
    const float* __restrict__ pose, float* __restrict__ partial) {
  __shared__ float lds[LDS_FLOATS];
  __shared__ float wsum[BLOCK / 64];

  const int tid = threadIdx.x;

  // ---- Stage 128 samples (32256 B) into LDS, coalesced float4 ----
  // Block base byte offset = blockIdx.x * 32256, multiple of 16 -> aligned.
  const float4* __restrict__ gsrc =
      (const float4*)(pose + (size_t)blockIdx.x * LDS_FLOATS);
  float4* ldst = (float4*)lds;

  float4 tmp[15];
#pragma unroll
  for (int i = 0; i < 15; ++i) tmp[i] = gsrc[tid + i * BLOCK];
  float4 tail;
  if (tid < TAIL) tail = gsrc[tid + 15 * BLOCK];
#pragma unroll
  for (int i = 0; i < 15; ++i) ldst[tid + i * BLOCK] = tmp[i];
  if (tid < TAIL) ldst[tid + 15 * BLOCK] = tail;

  __syncthreads();

  // ---- One sample per thread from LDS ----
  // Read addrs tid*63+k: bank = (k - tid) mod 32 -> 2 lanes/bank = free.
  const float* s = &lds[tid * FPS];
  float loss = 0.0f;

#pragma unroll
  for (int f = 0; f < 5; ++f) {
    const float* j = s + 12 * f;  // finger f: joints 4f..4f+4 -> floats 12f..12f+14
    const float j0x = j[0],  j0y = j[1],  j0z = j[2];
    const float j1x = j[3],  j1y = j[4],  j1z = j[5];
    const float j2x = j[6],  j2y = j[7],  j2z = j[8];
    const float j3x = j[9],  j3y = j[10], j3z = j[11];
    const float j4x = j[12], j4y = j[13], j4z = j[14];

    const float b1x = j1x - j0x, b1y = j1y - j0y, b1z = j1z - j0z;
    const float b2x = j2x - j1x, b2y = j2y - j1y, b2z = j2z - j1z;
    const float b3x = j3x - j2x, b3y = j3y - j2y, b3z = j3z - j2z;
    const float b4x = j4x - j3x, b4y = j4y - j3y, b4z = j4z - j3z;

    // rot_tip = cross(b4, b3); rot_mid = cross(b3, b2); rot_palm = cross(b2, b1)
    const float rtx = b4y * b3z - b4z * b3y;
    const float rty = b4z * b3x - b4x * b3z;
    const float rtz = b4x * b3y - b4y * b3x;
    const float rmx = b3y * b2z - b3z * b2y;
    const float rmy = b3z * b2x - b3x * b2z;
    const float rmz = b3x * b2y - b3y * b2x;
    const float rpx = b2y * b1z - b2z * b1y;
    const float rpy = b2z * b1x - b2x * b1z;
    const float rpz = b2x * b1y - b2y * b1x;

    const float coplane =
        (rpx + rmx) * b4x + (rpy + rmy) * b4y + (rpz + rmz) * b4z;
    const float vd1 = rtx * rmx + rty * rmy + rtz * rmz;
    const float vd2 = rpx * rmx + rpy * rmy + rpz * rmz;

    loss += coplane;
    if (vd1 < 0.0f) loss += vd1 * vd1;
    if (vd2 < 0.0f) loss += vd2 * vd2;
  }

  // ---- wave shuffle -> block LDS -> one partial store per block ----
#pragma unroll
  for (int o = 32; o > 0; o >>= 1) loss += __shfl_down(loss, o, 64);

  if ((tid & 63) == 0) wsum[tid >> 6] = loss;
  __syncthreads();
  if (tid == 0) {
    float blocksum = 0.0f;
#pragma unroll
    for (int w = 0; w < BLOCK / 64; ++w) blocksum += wsum[w];
    partial[blockIdx.x] = blocksum;
  }
}

// Reduce n partials (n = 4096) -> out[0]. Single block, 1024 threads.
__global__ __launch_bounds__(1024) void jal_reduce(
    const float* __restrict__ partial, float* __restrict__ out, int n) {
  __shared__ float wsum[16];
  const int tid = threadIdx.x;

  float s = 0.0f;
  for (int i = tid; i < n; i += 1024) s += partial[i];

#pragma unroll
  for (int o = 32; o > 0; o >>= 1) s += __shfl_down(s, o, 64);

  if ((tid & 63) == 0) wsum[tid >> 6] = s;
  __syncthreads();
  if (tid == 0) {
    float total = 0.0f;
#pragma unroll
    for (int w = 0; w < 16; ++w) total += wsum[w];
    out[0] = total;
  }
}

extern "C" void kernel_launch(void* const* d_in, const int* in_sizes, int n_in,
                              void* d_out, int out_size, void* d_ws, size_t ws_size,
                              hipStream_t stream) {
  const float* pose = (const float*)d_in[0];
  float* out = (float*)d_out;
  float* partial = (float*)d_ws;  // 4096 floats = 16 KB, well within ws_size
  const int B = in_sizes[0] / FPS;     // 524288
  const int grid = B / BLOCK;          // 4096, exact

  jal_partial<<<grid, BLOCK, 0, stream>>>(pose, partial);
  jal_reduce<<<1, 1024, 0, stream>>>(partial, out, grid);
}